// Round 1
// baseline (921.450 us; speedup 1.0000x reference)
//
#include <hip/hip_runtime.h>
#include <math.h>

// Problem constants
constexpr int KW      = 56;     // W / K dim
constexpr int NHEADS  = 8;
constexpr int NB      = 1792;   // 32*56 batch rows
constexpr int QKV_CH  = 128;    // 2*OUT_C
constexpr int SIM_CH  = 24;     // 3*HEADS
constexpr int RELW    = 111;    // 2K-1
constexpr int INC     = 64;
constexpr float EPS   = 1e-5f;

// ---------------- Kernel A: qkv = w @ x  + per-channel stats ----------------
__global__ __launch_bounds__(256) void k_qkv(const float* __restrict__ x,
                                             const float* __restrict__ w,
                                             float* __restrict__ qkv,
                                             float* __restrict__ sums) {
    __shared__ float xs[INC * KW];        // 3584 floats, xs[c*56+i]
    __shared__ float wt[INC * QKV_CH];    // 8192 floats, wt[c*128+o]
    __shared__ float s1[QKV_CH], s2[QKV_CH];
    const int b = blockIdx.x, tid = threadIdx.x;

    for (int i = tid; i < QKV_CH; i += 256) { s1[i] = 0.f; s2[i] = 0.f; }
    for (int idx = tid; idx < INC * KW; idx += 256) {
        int c = idx / KW, i = idx - c * KW;
        xs[idx] = x[c * 100352 + b * KW + i];
    }
    for (int idx = tid; idx < INC * QKV_CH; idx += 256) {
        int c = idx >> 7, o = idx & 127;
        wt[idx] = w[o * INC + c];
    }
    __syncthreads();

    const int o = tid & 127;        // channel
    const int part = tid >> 7;      // which half of i-range
    const int ib = part * 28;
    float acc[28];
#pragma unroll
    for (int i = 0; i < 28; ++i) acc[i] = 0.f;
    for (int c = 0; c < INC; ++c) {
        float wv = wt[c * QKV_CH + o];
        const float* xr = xs + c * KW + ib;
#pragma unroll
        for (int i = 0; i < 28; ++i) acc[i] += wv * xr[i];
    }
    float ls = 0.f, ls2 = 0.f;
    float* outp = qkv + (size_t)b * 7168 + o * KW + ib;
#pragma unroll
    for (int q = 0; q < 7; ++q) {
        float4 v = make_float4(acc[4*q], acc[4*q+1], acc[4*q+2], acc[4*q+3]);
        *(float4*)(outp + 4 * q) = v;
    }
#pragma unroll
    for (int i = 0; i < 28; ++i) { ls += acc[i]; ls2 += acc[i] * acc[i]; }
    atomicAdd(&s1[o], ls);
    atomicAdd(&s2[o], ls2);
    __syncthreads();
    for (int oo = tid; oo < QKV_CH; oo += 256) {
        atomicAdd(&sums[oo], s1[oo]);
        atomicAdd(&sums[QKV_CH + oo], s2[oo]);
    }
}

// ---------------- coef finalize: scale = g*rsqrt(var+eps), shift = b-mean*scale
__global__ void k_coef(const float* __restrict__ sums, const float* __restrict__ g,
                       const float* __restrict__ bb, float* __restrict__ coef,
                       int nch, float invM) {
    int o = blockIdx.x * blockDim.x + threadIdx.x;
    if (o < nch) {
        float mean = sums[o] * invM;
        float var  = fmaxf(sums[nch + o] * invM - mean * mean, 0.f);
        float sc   = g[o] * rsqrtf(var + EPS);
        coef[o] = sc;
        coef[nch + o] = bb[o] - mean * sc;
    }
}

// ---------------- Kernel C: qk/qr/kr stats (recompute, no materialization) ----
__global__ __launch_bounds__(256) void k_simstats(const float* __restrict__ qkv,
                                                  const float* __restrict__ rel,
                                                  const float* __restrict__ qcoef,
                                                  float* __restrict__ sums) {
    const int bg = blockIdx.x;
    const int b = bg >> 3, g = bg & 7;
    const int tid = threadIdx.x;
    __shared__ float qs[8 * KW];       // rows 0..3 = qhat, 4..7 = khat
    __shared__ float rl[8 * RELW];
    __shared__ float acc[6];
    if (tid < 6) acc[tid] = 0.f;
    for (int idx = tid; idx < 8 * KW; idx += 256) {
        int c = idx / KW;
        int o = g * 16 + c;
        qs[idx] = qkv[(size_t)b * 7168 + o * KW + (idx - c * KW)] * qcoef[o] + qcoef[QKV_CH + o];
    }
    for (int idx = tid; idx < 8 * RELW; idx += 256) rl[idx] = rel[idx];
    __syncthreads();

    float sqk = 0, sqk2 = 0, sqr = 0, sqr2 = 0, skr = 0, skr2 = 0;
    for (int idx = tid; idx < KW * KW; idx += 256) {
        int i = idx / KW, j = idx - i * KW;
        int dq = i - j + KW - 1;
        int dk = j - i + KW - 1;
        float qk = 0, qr = 0, kr = 0;
#pragma unroll
        for (int c = 0; c < 4; ++c) {
            float qv = qs[c * KW + i];
            float kv = qs[(4 + c) * KW + j];
            qk += qv * kv;
            qr += qv * rl[c * RELW + dq];
            kr += kv * rl[(4 + c) * RELW + dk];
        }
        qr *= 0.1f; kr *= 0.1f;
        sqk += qk; sqk2 += qk * qk;
        sqr += qr; sqr2 += qr * qr;
        skr += kr; skr2 += kr * kr;
    }
    float vals[6] = {sqk, sqk2, sqr, sqr2, skr, skr2};
#pragma unroll
    for (int v = 0; v < 6; ++v) {
        float xv = vals[v];
        for (int off = 32; off > 0; off >>= 1) xv += __shfl_down(xv, off);
        if ((tid & 63) == 0) atomicAdd(&acc[v], xv);
    }
    __syncthreads();
    if (tid < 3) {
        int ch = tid * 8 + g;   // qk -> g, qr -> 8+g, kr -> 16+g
        atomicAdd(&sums[ch],          acc[tid * 2]);
        atomicAdd(&sums[SIM_CH + ch], acc[tid * 2 + 1]);
    }
}

// ---------------- Kernel E: BN+sum+softmax+SV/SVE + out-stats ----------------
__global__ __launch_bounds__(256) void k_attn(const float* __restrict__ qkv,
                                              const float* __restrict__ rel,
                                              const float* __restrict__ qcoef,
                                              const float* __restrict__ scoef,
                                              float* __restrict__ so,
                                              float* __restrict__ osums) {
    const int bg = blockIdx.x;
    const int b = bg >> 3, g = bg & 7;
    const int tid = threadIdx.x;
    __shared__ float qs[16 * KW];          // qhat(0..3) khat(4..7) vhat(8..15)
    __shared__ float rl[16 * RELW];
    __shared__ float S[KW * 57];           // padded rows (57) to dodge bank conflicts
    __shared__ float os1[16], os2[16];
    if (tid < 16) { os1[tid] = 0.f; os2[tid] = 0.f; }
    for (int idx = tid; idx < 16 * KW; idx += 256) {
        int o = g * 16 + idx / KW;
        qs[idx] = qkv[(size_t)b * 7168 + g * 16 * KW + idx] * qcoef[o] + qcoef[QKV_CH + o];
    }
    for (int idx = tid; idx < 16 * RELW; idx += 256) rl[idx] = rel[idx];
    __syncthreads();

    const float aqk = scoef[g],      cqk = scoef[SIM_CH + g];
    const float aqr = scoef[8 + g],  cqr = scoef[SIM_CH + 8 + g];
    const float akr = scoef[16 + g], ckr = scoef[SIM_CH + 16 + g];
    const float cc = cqk + cqr + ckr;
    for (int idx = tid; idx < KW * KW; idx += 256) {
        int i = idx / KW, j = idx - i * KW;
        int dq = i - j + KW - 1;
        int dk = j - i + KW - 1;
        float qk = 0, qr = 0, kr = 0;
#pragma unroll
        for (int c = 0; c < 4; ++c) {
            float qv = qs[c * KW + i];
            float kv = qs[(4 + c) * KW + j];
            qk += qv * kv;
            qr += qv * rl[c * RELW + dq];
            kr += kv * rl[(4 + c) * RELW + dk];
        }
        S[i * 57 + j] = qk * aqk + (qr * 0.1f) * aqr + (kr * 0.1f) * akr + cc;
    }
    __syncthreads();
    // softmax over j for each row i
    if (tid < KW) {
        float* row = S + tid * 57;
        float m = row[0];
        for (int j = 1; j < KW; ++j) m = fmaxf(m, row[j]);
        float s = 0.f;
        for (int j = 0; j < KW; ++j) { float e = __expf(row[j] - m); row[j] = e; s += e; }
        float inv = 1.f / s;
        for (int j = 0; j < KW; ++j) row[j] *= inv;
    }
    __syncthreads();
    // sv[c][i], sve[c][i]
    for (int idx = tid; idx < 8 * KW; idx += 256) {
        int c = idx / KW, i = idx - c * KW;
        const float* srow = S + i * 57;
        const float* vrow = qs + (8 + c) * KW;
        const float* rrow = rl + (8 + c) * RELW + (i + KW - 1);  // index (i+55) - j
        float sv = 0.f, sve = 0.f;
        for (int j = 0; j < KW; ++j) {
            float sj = srow[j];
            sv  += sj * vrow[j];
            sve += sj * rrow[-j];
        }
        sve *= 0.1f;
        int o0 = g * 16 + 2 * c;
        so[(size_t)b * 7168 + o0 * KW + i]       = sv;
        so[(size_t)b * 7168 + (o0 + 1) * KW + i] = sve;
        atomicAdd(&os1[2 * c], sv);      atomicAdd(&os2[2 * c], sv * sv);
        atomicAdd(&os1[2 * c + 1], sve); atomicAdd(&os2[2 * c + 1], sve * sve);
    }
    __syncthreads();
    if (tid < 16) {
        int o = g * 16 + tid;
        atomicAdd(&osums[o],          os1[tid]);
        atomicAdd(&osums[QKV_CH + o], os2[tid]);
    }
}

// ---------------- Kernel G: out-BN + pair-sum + transpose store ----------------
__global__ __launch_bounds__(256) void k_out(const float* __restrict__ so,
                                             const float* __restrict__ ocoef,
                                             float* __restrict__ out) {
    int idx = blockIdx.x * 256 + threadIdx.x;   // exactly 6422528 threads
    int t = idx % KW;
    int rest = idx / KW;          // (oc*32+d)*56 + h
    int h = rest % KW;
    int rest2 = rest / KW;        // oc*32 + d
    int d = rest2 & 31;
    int oc = rest2 >> 5;
    int b = d * KW + h;
    int o0 = 2 * oc;
    float v0 = so[(size_t)b * 7168 + o0 * KW + t];
    float v1 = so[(size_t)b * 7168 + (o0 + 1) * KW + t];
    v0 = v0 * ocoef[o0]     + ocoef[QKV_CH + o0];
    v1 = v1 * ocoef[o0 + 1] + ocoef[QKV_CH + o0 + 1];
    out[idx] = v0 + v1;
}

extern "C" void kernel_launch(void* const* d_in, const int* in_sizes, int n_in,
                              void* d_out, int out_size, void* d_ws, size_t ws_size,
                              hipStream_t stream) {
    const float* x     = (const float*)d_in[0];
    const float* wqkv  = (const float*)d_in[1];
    const float* rel   = (const float*)d_in[2];
    const float* g_qkv = (const float*)d_in[3];
    const float* b_qkv = (const float*)d_in[4];
    const float* g_sim = (const float*)d_in[5];
    const float* b_sim = (const float*)d_in[6];
    const float* g_out = (const float*)d_in[7];
    const float* b_out = (const float*)d_in[8];
    float* out = (float*)d_out;
    float* ws = (float*)d_ws;

    float* qkv_raw  = ws;                       // 12,845,056 floats
    float* so_raw   = ws + 12845056;            // 12,845,056 floats
    float* stats    = ws + 25690112;
    float* qkv_sums = stats;                    // 256
    float* sim_sums = stats + 256;              // 48
    float* out_sums = stats + 304;              // 256
    float* qkv_coef = stats + 560;              // 256
    float* sim_coef = stats + 816;              // 48
    float* out_coef = stats + 864;              // 256

    hipMemsetAsync(stats, 0, 560 * sizeof(float), stream);

    k_qkv<<<NB, 256, 0, stream>>>(x, wqkv, qkv_raw, qkv_sums);
    k_coef<<<1, 128, 0, stream>>>(qkv_sums, g_qkv, b_qkv, qkv_coef, QKV_CH,
                                  1.0f / 100352.0f);
    k_simstats<<<NB * NHEADS, 256, 0, stream>>>(qkv_raw, rel, qkv_coef, sim_sums);
    k_coef<<<1, 128, 0, stream>>>(sim_sums, g_sim, b_sim, sim_coef, SIM_CH,
                                  1.0f / 5619712.0f);
    k_attn<<<NB * NHEADS, 256, 0, stream>>>(qkv_raw, rel, qkv_coef, sim_coef,
                                            so_raw, out_sums);
    k_coef<<<1, 128, 0, stream>>>(out_sums, g_out, b_out, out_coef, QKV_CH,
                                  1.0f / 100352.0f);
    k_out<<<25088, 256, 0, stream>>>(so_raw, out_coef, out);
}